// Round 7
// baseline (1743.508 us; speedup 1.0000x reference)
//
#include <hip/hip_runtime.h>

// Transcoder forward: y_hat, hidden_acts, aux_loss(=0), x_norm
// B=4096, D_IN=2048, D_OUT=2048, N_FEAT=16384, TOP_K=32. All fp32 in/out.
// Encoder GEMM = bf16x2-split MFMA (4 products). Error model: split-repr
// ~2*2^-18 + accum ~5.4e-8 => ~1.2e-7 abs on pre_acts; comparable to the
// f32 reorder noise any reimplementation has vs the JAX reference.
// Cost model (per 128x128 block K-step): MFMA 256x4.85=1242 clk (bound),
// LDS read 512 clk, LDS write 256 clk -> MFMA-bound, ~2.4x LDS headroom.
// ws: region1 (128MB) = Wh/Wl during GEMM, aliased by WT after; region2 = Xh/Xl (32MB).

constexpr int BROWS  = 4096;
constexpr int D_IN   = 2048;
constexpr int D_OUT  = 2048;
constexpr int N_FEAT = 16384;
constexpr int TOPK   = 32;

static_assert((size_t)N_FEAT * D_IN * 2 * 2 == (size_t)N_FEAT * D_OUT * 4,
              "WT must exactly alias Wh+Wl");

using bf16x8 = __attribute__((ext_vector_type(8))) short;   // 8 bf16 in 4 VGPRs
using f32x4  = __attribute__((ext_vector_type(4))) float;

__device__ __forceinline__ unsigned fkey(float x) {
    unsigned u = __float_as_uint(x);
    return (u & 0x80000000u) ? ~u : (u | 0x80000000u);   // order-preserving
}

__device__ __forceinline__ unsigned short f2bf(float f) {
    unsigned u = __float_as_uint(f);
    u += 0x7FFFu + ((u >> 16) & 1u);   // round-to-nearest-even
    return (unsigned short)(u >> 16);
}

__device__ __forceinline__ void split2(float f, unsigned short& h, unsigned short& l) {
    unsigned short hb = f2bf(f);
    float hf = __uint_as_float((unsigned)hb << 16);
    h = hb;
    l = f2bf(f - hf);                  // residual computed exactly in fp32
}

// ---------------- Kernel 1 (full path): row norm + split x into bf16 hi/lo ----------------
__global__ __launch_bounds__(256) void norm_split_x_kernel(
    const float* __restrict__ x, float* __restrict__ xn, float* __restrict__ aux,
    unsigned short* __restrict__ Xh, unsigned short* __restrict__ Xl)
{
    const int row = blockIdx.x, tid = threadIdx.x;
    const float4* xr = reinterpret_cast<const float4*>(x + (size_t)row * D_IN);
    float4 v0 = xr[tid], v1 = xr[tid + 256];
    float ss = v0.x*v0.x + v0.y*v0.y + v0.z*v0.z + v0.w*v0.w
             + v1.x*v1.x + v1.y*v1.y + v1.z*v1.z + v1.w*v1.w;
    #pragma unroll
    for (int off = 32; off > 0; off >>= 1) ss += __shfl_down(ss, off);
    __shared__ float wsum[4];
    __shared__ float s_norm;
    if ((tid & 63) == 0) wsum[tid >> 6] = ss;
    __syncthreads();
    if (tid == 0) {
        float nr = sqrtf(wsum[0] + wsum[1] + wsum[2] + wsum[3]);
        xn[row] = nr;
        s_norm  = nr;
    }
    if (row == 0 && tid == 0) aux[0] = 0.0f;
    __syncthreads();
    const float s = 1.0f / (s_norm + 1e-8f);
    ushort4* oh = reinterpret_cast<ushort4*>(Xh + (size_t)row * D_IN);
    ushort4* ol = reinterpret_cast<ushort4*>(Xl + (size_t)row * D_IN);
    ushort4 h, l;
    split2(v0.x*s, h.x, l.x); split2(v0.y*s, h.y, l.y);
    split2(v0.z*s, h.z, l.z); split2(v0.w*s, h.w, l.w);
    oh[tid] = h; ol[tid] = l;
    split2(v1.x*s, h.x, l.x); split2(v1.y*s, h.y, l.y);
    split2(v1.z*s, h.z, l.z); split2(v1.w*s, h.w, l.w);
    oh[tid + 256] = h; ol[tid + 256] = l;
}

// ---------------- Kernel 1-alt (fallback): row norms only ----------------
__global__ __launch_bounds__(256) void norm_kernel(
    const float* __restrict__ x, float* __restrict__ xn, float* __restrict__ aux)
{
    const int row = blockIdx.x, tid = threadIdx.x;
    const float4* xr = reinterpret_cast<const float4*>(x + (size_t)row * D_IN);
    float4 v0 = xr[tid], v1 = xr[tid + 256];
    float ss = v0.x*v0.x + v0.y*v0.y + v0.z*v0.z + v0.w*v0.w
             + v1.x*v1.x + v1.y*v1.y + v1.z*v1.z + v1.w*v1.w;
    #pragma unroll
    for (int off = 32; off > 0; off >>= 1) ss += __shfl_down(ss, off);
    __shared__ float wsum[4];
    if ((tid & 63) == 0) wsum[tid >> 6] = ss;
    __syncthreads();
    if (tid == 0) xn[row] = sqrtf(wsum[0] + wsum[1] + wsum[2] + wsum[3]);
    if (row == 0 && tid == 0) aux[0] = 0.0f;
}

// ---------------- Kernel 1c: split W_enc into bf16 hi/lo ----------------
__global__ __launch_bounds__(256) void split_w_kernel(
    const float* __restrict__ W,
    unsigned short* __restrict__ Wh, unsigned short* __restrict__ Wl)
{
    const int row = blockIdx.x, tid = threadIdx.x;
    const float4* wr = reinterpret_cast<const float4*>(W + (size_t)row * D_IN);
    ushort4* oh = reinterpret_cast<ushort4*>(Wh + (size_t)row * D_IN);
    ushort4* ol = reinterpret_cast<ushort4*>(Wl + (size_t)row * D_IN);
    #pragma unroll
    for (int t = 0; t < 2; ++t) {
        float4 v = wr[tid + t*256];
        ushort4 h, l;
        split2(v.x, h.x, l.x); split2(v.y, h.y, l.y);
        split2(v.z, h.z, l.z); split2(v.w, h.w, l.w);
        oh[tid + t*256] = h; ol[tid + t*256] = l;
    }
}

// ---------------- Kernel 2: encoder GEMM, bf16x2-split MFMA (4 products) ----------------
// C[m,n] = sum_k (Ah+Al)[m,k]*(Bh+Bl)[n,k] + bias[n]
// m97-verified structure: 128x128 tile, BK=32, 4 waves (2x2 of 64x64),
// 16x16x32 MFMA, linear LDS + global_load_lds width 16, 2 barriers/K-step.
#define GLDS16(src, dst) \
    __builtin_amdgcn_global_load_lds( \
        (const __attribute__((address_space(1))) unsigned int*)(src), \
        (__attribute__((address_space(3))) unsigned int*)(dst), 16, 0, 0)

__global__ __launch_bounds__(256) void enc_mfma_kernel(
    const unsigned short* __restrict__ Xh, const unsigned short* __restrict__ Xl,
    const unsigned short* __restrict__ Wh, const unsigned short* __restrict__ Wl,
    const float* __restrict__ bias, float* __restrict__ C)
{
    __shared__ unsigned short sAh[128*32], sAl[128*32], sBh[128*32], sBl[128*32];

    // XCD-aware bijective swizzle (nwg=4096, %8==0): 512-block chunks per XCD.
    const int flat = blockIdx.y * gridDim.x + blockIdx.x;
    const int swz  = (flat & 7) * 512 + (flat >> 3);
    const int bm = swz >> 7;      // 0..31  (4 consecutive bm per XCD chunk)
    const int bn = swz & 127;     // 0..127

    const int tid  = threadIdx.x;
    const int wid  = tid >> 6;    // wave 0..3
    const int lane = tid & 63;
    const int wm = wid >> 1, wn = wid & 1;

    // staging: lane i -> row i>>2, 16B segment (i&3). LDS linear [row][32 bf16]:
    // dest(lane)=base+lane*16 == (i>>2)*64 + (i&3)*16. One GLDS16 = 16 rows.
    const int srow = lane >> 2;
    const int scol = (lane & 3) * 8;
    const size_t arow = (size_t)bm*128 + wid*32 + srow;
    const size_t brow = (size_t)bn*128 + wid*32 + srow;
    const unsigned short* gAh = Xh + arow*D_IN + scol;
    const unsigned short* gAl = Xl + arow*D_IN + scol;
    const unsigned short* gBh = Wh + brow*D_IN + scol;
    const unsigned short* gBl = Wl + brow*D_IN + scol;
    const size_t rstep = (size_t)16 * D_IN;   // +16 rows (chunk 1)
    const int ldsA = wid * 1024;              // rows wid*32..wid*32+31

    const int fr = lane & 15;                 // fragment row/col
    const int fk = (lane >> 4) * 8;           // fragment k-offset

    f32x4 acc[4][4] = {};

    for (int k0 = 0; k0 < D_IN; k0 += 32) {
        GLDS16(gAh + k0,         sAh + ldsA);
        GLDS16(gAh + k0 + rstep, sAh + ldsA + 512);
        GLDS16(gAl + k0,         sAl + ldsA);
        GLDS16(gAl + k0 + rstep, sAl + ldsA + 512);
        GLDS16(gBh + k0,         sBh + ldsA);
        GLDS16(gBh + k0 + rstep, sBh + ldsA + 512);
        GLDS16(gBl + k0,         sBl + ldsA);
        GLDS16(gBl + k0 + rstep, sBl + ldsA + 512);
        __syncthreads();   // compiler drains vmcnt(0)+lgkmcnt(0) before s_barrier

        bf16x8 ah[4], al[4], bh[4], bl[4];
        #pragma unroll
        for (int i = 0; i < 4; ++i) {
            const int ar = (wm*64 + i*16 + fr)*32 + fk;
            ah[i] = *reinterpret_cast<const bf16x8*>(&sAh[ar]);
            al[i] = *reinterpret_cast<const bf16x8*>(&sAl[ar]);
            const int br = (wn*64 + i*16 + fr)*32 + fk;
            bh[i] = *reinterpret_cast<const bf16x8*>(&sBh[br]);
            bl[i] = *reinterpret_cast<const bf16x8*>(&sBl[br]);
        }
        // 16 independent 4-deep chains -> ample ILP for the MFMA pipe.
        #pragma unroll
        for (int i = 0; i < 4; ++i)
            #pragma unroll
            for (int j = 0; j < 4; ++j) {
                acc[i][j] = __builtin_amdgcn_mfma_f32_16x16x32_bf16(ah[i], bh[j], acc[i][j], 0, 0, 0);
                acc[i][j] = __builtin_amdgcn_mfma_f32_16x16x32_bf16(ah[i], bl[j], acc[i][j], 0, 0, 0);
                acc[i][j] = __builtin_amdgcn_mfma_f32_16x16x32_bf16(al[i], bh[j], acc[i][j], 0, 0, 0);
                acc[i][j] = __builtin_amdgcn_mfma_f32_16x16x32_bf16(al[i], bl[j], acc[i][j], 0, 0, 0);
            }
        __syncthreads();   // protect LDS before next stage
    }

    // epilogue: C/D layout col=lane&15, row=(lane>>4)*4+reg (m89/m91-verified)
    const int crow = bm*128 + wm*64;
    const int ccol = bn*128 + wn*64;
    #pragma unroll
    for (int j = 0; j < 4; ++j) {
        const int col = ccol + j*16 + fr;
        const float bv = bias[col];
        #pragma unroll
        for (int i = 0; i < 4; ++i) {
            const int r0 = crow + i*16 + (lane >> 4)*4;
            #pragma unroll
            for (int r = 0; r < 4; ++r)
                C[(size_t)(r0 + r)*N_FEAT + col] = acc[i][j][r] + bv;
        }
    }
}

// ---------------- Kernel 2-alt: fp32 SIMT GEMM (fallback when ws small) ----------------
constexpr int BM = 128, BN = 128, BK = 16;
__global__ __launch_bounds__(256) void enc_gemm_kernel(
    const float* __restrict__ X, const float* __restrict__ W,
    const float* __restrict__ bias, const float* __restrict__ xn,
    float* __restrict__ C)
{
    __shared__ float sA[BK][BM + 4];
    __shared__ float sB[BK][BN + 4];
    const int tid = threadIdx.x;
    const int bn = blockIdx.x, bm = blockIdx.y;
    const int tx = tid & 15, ty = tid >> 4;
    const int lrow = tid >> 2;
    const int lq   = (tid & 3) * 4;

    const int arow0 = bm * BM + lrow;
    const float* Ap0 = X + (size_t)arow0 * D_IN + lq;
    const float* Ap1 = Ap0 + (size_t)64 * D_IN;
    const float* Bp0 = W + (size_t)(bn * BN + lrow) * D_IN + lq;
    const float* Bp1 = Bp0 + (size_t)64 * D_IN;

    const float s0 = 1.0f / (xn[arow0] + 1e-8f);
    const float s1 = 1.0f / (xn[arow0 + 64] + 1e-8f);

    float acc[8][8] = {};

    for (int k0 = 0; k0 < D_IN; k0 += BK) {
        float4 a0 = *reinterpret_cast<const float4*>(Ap0 + k0);
        float4 a1 = *reinterpret_cast<const float4*>(Ap1 + k0);
        float4 b0 = *reinterpret_cast<const float4*>(Bp0 + k0);
        float4 b1 = *reinterpret_cast<const float4*>(Bp1 + k0);
        if (k0) __syncthreads();
        sA[lq+0][lrow]    = a0.x * s0; sA[lq+1][lrow]    = a0.y * s0;
        sA[lq+2][lrow]    = a0.z * s0; sA[lq+3][lrow]    = a0.w * s0;
        sA[lq+0][lrow+64] = a1.x * s1; sA[lq+1][lrow+64] = a1.y * s1;
        sA[lq+2][lrow+64] = a1.z * s1; sA[lq+3][lrow+64] = a1.w * s1;
        sB[lq+0][lrow]    = b0.x;      sB[lq+1][lrow]    = b0.y;
        sB[lq+2][lrow]    = b0.z;      sB[lq+3][lrow]    = b0.w;
        sB[lq+0][lrow+64] = b1.x;      sB[lq+1][lrow+64] = b1.y;
        sB[lq+2][lrow+64] = b1.z;      sB[lq+3][lrow+64] = b1.w;
        __syncthreads();
        #pragma unroll
        for (int k = 0; k < BK; ++k) {
            float av[8], bv[8];
            *reinterpret_cast<float4*>(&av[0]) = *reinterpret_cast<const float4*>(&sA[k][ty*8]);
            *reinterpret_cast<float4*>(&av[4]) = *reinterpret_cast<const float4*>(&sA[k][ty*8+4]);
            *reinterpret_cast<float4*>(&bv[0]) = *reinterpret_cast<const float4*>(&sB[k][tx*8]);
            *reinterpret_cast<float4*>(&bv[4]) = *reinterpret_cast<const float4*>(&sB[k][tx*8+4]);
            #pragma unroll
            for (int i = 0; i < 8; ++i)
                #pragma unroll
                for (int j = 0; j < 8; ++j)
                    acc[i][j] += av[i] * bv[j];
        }
    }

    const int crow0 = bm * BM + ty * 8;
    const int ccol0 = bn * BN + tx * 8;
    float bb[8];
    *reinterpret_cast<float4*>(&bb[0]) = *reinterpret_cast<const float4*>(bias + ccol0);
    *reinterpret_cast<float4*>(&bb[4]) = *reinterpret_cast<const float4*>(bias + ccol0 + 4);
    #pragma unroll
    for (int i = 0; i < 8; ++i) {
        float o[8];
        #pragma unroll
        for (int j = 0; j < 8; ++j) o[j] = acc[i][j] + bb[j];
        float* cp = C + (size_t)(crow0 + i) * N_FEAT + ccol0;
        *reinterpret_cast<float4*>(cp)     = *reinterpret_cast<const float4*>(&o[0]);
        *reinterpret_cast<float4*>(cp + 4) = *reinterpret_cast<const float4*>(&o[4]);
    }
}

// ---------------- Kernel 3: exact top-k(32) per row, in-place; optional fused decode ----------------
// Radix-select on 11-bit key prefix, exact tie-break by lowest index (matches lax.top_k).
// DECODE=true: after scatter, compute y[row,:] = (sum relu(v_j)*WT[f_j,:] + bdec) * xn[row].
constexpr int NBINS = 2048;
constexpr int MAXC  = 512;

template <bool DECODE>
__global__ __launch_bounds__(256) void topk_kernel(
    float* __restrict__ hidden, const float* __restrict__ WT,
    const float* __restrict__ bdec, const float* __restrict__ xn,
    float* __restrict__ y)
{
    __shared__ unsigned hist[NBINS];
    __shared__ unsigned tsum[256];
    __shared__ unsigned sufs[256];
    __shared__ unsigned cand_key[MAXC];
    __shared__ float    cand_val[MAXC];
    __shared__ int      cand_idx[MAXC];
    __shared__ float    top_val[TOPK];
    __shared__ int      top_idx[TOPK];
    __shared__ unsigned cnt_top, cnt_cand;
    __shared__ int binB_s;
    __shared__ unsigned above_s;
    __shared__ unsigned long long skey_s[256];
    __shared__ int slot_s[256];

    const int row = blockIdx.x, tid = threadIdx.x;
    float* rowp = hidden + (size_t)row * N_FEAT;
    const float4* row4 = reinterpret_cast<const float4*>(rowp);

    for (int i = tid; i < NBINS; i += 256) hist[i] = 0u;
    if (tid == 0) { cnt_top = 0u; cnt_cand = 0u; }
    __syncthreads();

    // pass 1: histogram of top-11-bit keys
    for (int i = tid; i < N_FEAT/4; i += 256) {
        float4 v = row4[i];
        atomicAdd(&hist[fkey(v.x) >> 21], 1u);
        atomicAdd(&hist[fkey(v.y) >> 21], 1u);
        atomicAdd(&hist[fkey(v.z) >> 21], 1u);
        atomicAdd(&hist[fkey(v.w) >> 21], 1u);
    }
    __syncthreads();

    // suffix sums over 8-bin groups to locate threshold bin
    unsigned s = 0;
    #pragma unroll
    for (int j = 0; j < 8; ++j) s += hist[tid*8 + j];
    tsum[tid] = s;
    __syncthreads();
    unsigned suf = 0;
    for (int u = 0; u < 256; ++u) if (u >= tid) suf += tsum[u];
    sufs[tid] = suf;
    __syncthreads();
    unsigned nxt = (tid == 255) ? 0u : sufs[tid + 1];
    if (suf >= (unsigned)TOPK && nxt < (unsigned)TOPK) {  // exactly one thread
        unsigned cum = nxt;
        for (int j = 7; j >= 0; --j) {
            int b = tid*8 + j;
            unsigned h = hist[b];
            if (cum + h >= (unsigned)TOPK) { binB_s = b; above_s = cum; break; }
            cum += h;
        }
    }
    __syncthreads();
    const int binB = binB_s;
    const unsigned above = above_s;

    // pass 2 (L2-hot re-read): definite top-k (bin > binB) + boundary candidates
    for (int i = tid; i < N_FEAT/4; i += 256) {
        float4 v = row4[i];
        float vals[4] = {v.x, v.y, v.z, v.w};
        #pragma unroll
        for (int c = 0; c < 4; ++c) {
            unsigned key = fkey(vals[c]);
            int bin = (int)(key >> 21);
            if (bin > binB) {
                unsigned p = atomicAdd(&cnt_top, 1u);
                top_val[p] = vals[c]; top_idx[p] = i*4 + c;
            } else if (bin == binB) {
                unsigned p = atomicAdd(&cnt_cand, 1u);
                if (p < (unsigned)MAXC) {
                    cand_key[p] = key; cand_val[p] = vals[c]; cand_idx[p] = i*4 + c;
                }
            }
        }
    }
    __syncthreads();
    int ncand = (int)cnt_cand; if (ncand > MAXC) ncand = MAXC;
    const int r = TOPK - (int)above;

    // select r largest boundary candidates (key desc, idx asc on ties)
    for (int sel = 0; sel < r; ++sel) {
        unsigned long long best = 0ull; int bslot = -1;
        for (int c = tid; c < ncand; c += 256) {
            unsigned k2 = cand_key[c];
            if (k2 == 0u) continue;  // taken
            unsigned long long sk =
                ((unsigned long long)k2 << 32) | (unsigned)(~(unsigned)cand_idx[c]);
            if (sk > best) { best = sk; bslot = c; }
        }
        skey_s[tid] = best; slot_s[tid] = bslot;
        __syncthreads();
        for (int st = 128; st > 0; st >>= 1) {
            if (tid < st && skey_s[tid + st] > skey_s[tid]) {
                skey_s[tid] = skey_s[tid + st]; slot_s[tid] = slot_s[tid + st];
            }
            __syncthreads();
        }
        if (tid == 0) {
            int sl = slot_s[0];
            cand_key[sl] = 0u;
            top_val[(int)above + sel] = cand_val[sl];
            top_idx[(int)above + sel] = cand_idx[sl];
        }
        __syncthreads();
    }

    // zero the row, scatter relu(topk)
    float4 z = make_float4(0.f, 0.f, 0.f, 0.f);
    float4* w4 = reinterpret_cast<float4*>(rowp);
    for (int i = tid; i < N_FEAT/4; i += 256) w4[i] = z;
    __syncthreads();
    if (tid < TOPK) rowp[top_idx[tid]] = fmaxf(top_val[tid], 0.0f);

    if (DECODE) {
        // fused decode: nz list already in LDS — saves the 256MB hidden re-scan
        // and one launch vs a separate decode kernel.
        const float4* b4 = reinterpret_cast<const float4*>(bdec);
        float4 acc0 = b4[tid], acc1 = b4[tid + 256];
        #pragma unroll 1
        for (int j = 0; j < TOPK; ++j) {
            const float v = fmaxf(top_val[j], 0.0f);   // uniform across block
            if (v == 0.0f) continue;
            const float4* wr = reinterpret_cast<const float4*>(
                WT + (size_t)top_idx[j] * D_OUT);
            float4 w0 = wr[tid], w1 = wr[tid + 256];
            acc0.x += v*w0.x; acc0.y += v*w0.y; acc0.z += v*w0.z; acc0.w += v*w0.w;
            acc1.x += v*w1.x; acc1.y += v*w1.y; acc1.z += v*w1.z; acc1.w += v*w1.w;
        }
        const float xs = xn[row];
        acc0.x *= xs; acc0.y *= xs; acc0.z *= xs; acc0.w *= xs;
        acc1.x *= xs; acc1.y *= xs; acc1.z *= xs; acc1.w *= xs;
        float4* y4 = reinterpret_cast<float4*>(y + (size_t)row * D_OUT);
        y4[tid] = acc0; y4[tid + 256] = acc1;
    }
}

// ---------------- Kernel 4: transpose W_dec (D_OUT,N_FEAT)->(N_FEAT,D_OUT) ----------------
__global__ __launch_bounds__(256) void transpose_kernel(
    const float* __restrict__ W, float* __restrict__ WT)
{
    __shared__ float tile[32][33];
    const int f0 = blockIdx.x * 32, d0 = blockIdx.y * 32;
    const int tx = threadIdx.x & 31, ty = threadIdx.x >> 5;  // ty 0..7
    #pragma unroll
    for (int s2 = 0; s2 < 32; s2 += 8)
        tile[ty + s2][tx] = W[(size_t)(d0 + ty + s2) * N_FEAT + f0 + tx];
    __syncthreads();
    #pragma unroll
    for (int s2 = 0; s2 < 32; s2 += 8)
        WT[(size_t)(f0 + ty + s2) * D_OUT + d0 + tx] = tile[tx][ty + s2];
}

// ---------------- Kernel 5 (tiny-ws fallback): strided column-gather decode ----------------
__global__ __launch_bounds__(256) void decode_g_kernel(
    const float* __restrict__ Wd, const float* __restrict__ hidden,
    const float* __restrict__ bdec, const float* __restrict__ xn,
    float* __restrict__ y)
{
    __shared__ float nzv[64]; __shared__ int nzi[64]; __shared__ int nzc;
    const int row = blockIdx.x, tid = threadIdx.x;
    if (tid == 0) nzc = 0;
    __syncthreads();
    const float4* h4 = reinterpret_cast<const float4*>(hidden + (size_t)row * N_FEAT);
    for (int i = tid; i < N_FEAT/4; i += 256) {
        float4 v = h4[i];
        if (v.x != 0.f) { int p = atomicAdd(&nzc, 1); if (p < 64) { nzv[p] = v.x; nzi[p] = i*4;   } }
        if (v.y != 0.f) { int p = atomicAdd(&nzc, 1); if (p < 64) { nzv[p] = v.y; nzi[p] = i*4+1; } }
        if (v.z != 0.f) { int p = atomicAdd(&nzc, 1); if (p < 64) { nzv[p] = v.z; nzi[p] = i*4+2; } }
        if (v.w != 0.f) { int p = atomicAdd(&nzc, 1); if (p < 64) { nzv[p] = v.w; nzi[p] = i*4+3; } }
    }
    __syncthreads();
    int cnt = nzc; if (cnt > 64) cnt = 64;
    const int d0 = tid * 4, d1 = d0 + 1024;
    float a[8];
    a[0]=bdec[d0]; a[1]=bdec[d0+1]; a[2]=bdec[d0+2]; a[3]=bdec[d0+3];
    a[4]=bdec[d1]; a[5]=bdec[d1+1]; a[6]=bdec[d1+2]; a[7]=bdec[d1+3];
    for (int j = 0; j < cnt; ++j) {
        float v = nzv[j]; int f = nzi[j];
        a[0] += v * Wd[(size_t)(d0+0)*N_FEAT + f];
        a[1] += v * Wd[(size_t)(d0+1)*N_FEAT + f];
        a[2] += v * Wd[(size_t)(d0+2)*N_FEAT + f];
        a[3] += v * Wd[(size_t)(d0+3)*N_FEAT + f];
        a[4] += v * Wd[(size_t)(d1+0)*N_FEAT + f];
        a[5] += v * Wd[(size_t)(d1+1)*N_FEAT + f];
        a[6] += v * Wd[(size_t)(d1+2)*N_FEAT + f];
        a[7] += v * Wd[(size_t)(d1+3)*N_FEAT + f];
    }
    const float xs = xn[row];
    float* yr = y + (size_t)row * D_OUT;
    yr[d0]=a[0]*xs; yr[d0+1]=a[1]*xs; yr[d0+2]=a[2]*xs; yr[d0+3]=a[3]*xs;
    yr[d1]=a[4]*xs; yr[d1+1]=a[5]*xs; yr[d1+2]=a[6]*xs; yr[d1+3]=a[7]*xs;
}

extern "C" void kernel_launch(void* const* d_in, const int* in_sizes, int n_in,
                              void* d_out, int out_size, void* d_ws, size_t ws_size,
                              hipStream_t stream)
{
    const float* x     = (const float*)d_in[0];
    const float* W_enc = (const float*)d_in[1];
    const float* b_enc = (const float*)d_in[2];
    const float* W_dec = (const float*)d_in[3];
    const float* b_dec = (const float*)d_in[4];

    float* out    = (float*)d_out;
    float* y      = out;                                   // (B, D_OUT)
    float* hidden = out + (size_t)BROWS * D_OUT;           // (B, N_FEAT)
    float* aux    = hidden + (size_t)BROWS * N_FEAT;       // scalar
    float* xn     = aux + 1;                               // (B,)

    // ws layout: region1 (128MB) = Wh,Wl (bf16) during GEMM, WT (f32) after
    //            region2 (32MB)  = Xh,Xl (bf16)
    const size_t nW = (size_t)N_FEAT * D_IN;               // 33,554,432 elems
    const size_t nX = (size_t)BROWS * D_IN;                // 8,388,608 elems
    unsigned short* Wh = (unsigned short*)d_ws;
    unsigned short* Wl = Wh + nW;
    float*          WT = (float*)d_ws;                     // aliases Wh/Wl (temporally disjoint)
    unsigned short* Xh = (unsigned short*)(Wl + nW);
    unsigned short* Xl = Xh + nX;
    const size_t need_full = 2*nW*sizeof(unsigned short)   // region1: 128MB (== N_FEAT*D_OUT*4)
                           + 2*nX*sizeof(unsigned short);  // region2: 32MB  -> 160MB total
    const size_t need_wt   = (size_t)N_FEAT*D_OUT*sizeof(float);     // 128MB

    if (ws_size >= need_full) {
        norm_split_x_kernel<<<BROWS, 256, 0, stream>>>(x, xn, aux, Xh, Xl);
        split_w_kernel<<<N_FEAT, 256, 0, stream>>>(W_enc, Wh, Wl);
        enc_mfma_kernel<<<dim3(N_FEAT/128, BROWS/128), 256, 0, stream>>>(
            Xh, Xl, Wh, Wl, b_enc, hidden);
        // transpose AFTER the GEMM: WT overwrites the Wh/Wl region
        transpose_kernel<<<dim3(N_FEAT/32, D_OUT/32), 256, 0, stream>>>(W_dec, WT);
        topk_kernel<true><<<BROWS, 256, 0, stream>>>(hidden, WT, b_dec, xn, y);
    } else if (ws_size >= need_wt) {
        float* WT0 = (float*)d_ws;
        norm_kernel<<<BROWS, 256, 0, stream>>>(x, xn, aux);
        enc_gemm_kernel<<<dim3(N_FEAT/BN, BROWS/BM), 256, 0, stream>>>(
            x, W_enc, b_enc, xn, hidden);
        transpose_kernel<<<dim3(N_FEAT/32, D_OUT/32), 256, 0, stream>>>(W_dec, WT0);
        topk_kernel<true><<<BROWS, 256, 0, stream>>>(hidden, WT0, b_dec, xn, y);
    } else {
        norm_kernel<<<BROWS, 256, 0, stream>>>(x, xn, aux);
        enc_gemm_kernel<<<dim3(N_FEAT/BN, BROWS/BM), 256, 0, stream>>>(
            x, W_enc, b_enc, xn, hidden);
        topk_kernel<false><<<BROWS, 256, 0, stream>>>(hidden, nullptr, nullptr, nullptr, nullptr);
        decode_g_kernel<<<BROWS, 256, 0, stream>>>(W_dec, hidden, b_dec, xn, y);
    }
}

// Round 8
// 1640.087 us; speedup vs baseline: 1.0631x; 1.0631x over previous
//
#include <hip/hip_runtime.h>

// Transcoder forward: y_hat, hidden_acts, aux_loss(=0), x_norm
// B=4096, D_IN=2048, D_OUT=2048, N_FEAT=16384, TOP_K=32. All fp32 in/out.
// Encoder GEMM = bf16x2-split MFMA (3 products: hh + hl + lh).
// R7 measured: 1743us total, enc=1013us, MfmaUtil 50%, BANK_CONFLICT 6.7e7.
// R8: both-sides LDS XOR swizzle (pre-swizzled GLDS source + swizzled read,
// rule #21) kills the ~4x ds_read inflation; drop al*bl (absmax 0.29 passed
// -> accuracy headroom huge). Predict enc ~650us, conflicts ~0.
// ws: region1 (128MB) = Wh/Wl during GEMM, aliased by WT after; region2 = Xh/Xl (32MB).

constexpr int BROWS  = 4096;
constexpr int D_IN   = 2048;
constexpr int D_OUT  = 2048;
constexpr int N_FEAT = 16384;
constexpr int TOPK   = 32;

static_assert((size_t)N_FEAT * D_IN * 2 * 2 == (size_t)N_FEAT * D_OUT * 4,
              "WT must exactly alias Wh+Wl");

using bf16x8 = __attribute__((ext_vector_type(8))) short;   // 8 bf16 in 4 VGPRs
using f32x4  = __attribute__((ext_vector_type(4))) float;

__device__ __forceinline__ unsigned fkey(float x) {
    unsigned u = __float_as_uint(x);
    return (u & 0x80000000u) ? ~u : (u | 0x80000000u);   // order-preserving
}

__device__ __forceinline__ unsigned short f2bf(float f) {
    unsigned u = __float_as_uint(f);
    u += 0x7FFFu + ((u >> 16) & 1u);   // round-to-nearest-even
    return (unsigned short)(u >> 16);
}

__device__ __forceinline__ void split2(float f, unsigned short& h, unsigned short& l) {
    unsigned short hb = f2bf(f);
    float hf = __uint_as_float((unsigned)hb << 16);
    h = hb;
    l = f2bf(f - hf);                  // residual computed exactly in fp32
}

// ---------------- Kernel 1 (full path): row norm + split x into bf16 hi/lo ----------------
__global__ __launch_bounds__(256) void norm_split_x_kernel(
    const float* __restrict__ x, float* __restrict__ xn, float* __restrict__ aux,
    unsigned short* __restrict__ Xh, unsigned short* __restrict__ Xl)
{
    const int row = blockIdx.x, tid = threadIdx.x;
    const float4* xr = reinterpret_cast<const float4*>(x + (size_t)row * D_IN);
    float4 v0 = xr[tid], v1 = xr[tid + 256];
    float ss = v0.x*v0.x + v0.y*v0.y + v0.z*v0.z + v0.w*v0.w
             + v1.x*v1.x + v1.y*v1.y + v1.z*v1.z + v1.w*v1.w;
    #pragma unroll
    for (int off = 32; off > 0; off >>= 1) ss += __shfl_down(ss, off);
    __shared__ float wsum[4];
    __shared__ float s_norm;
    if ((tid & 63) == 0) wsum[tid >> 6] = ss;
    __syncthreads();
    if (tid == 0) {
        float nr = sqrtf(wsum[0] + wsum[1] + wsum[2] + wsum[3]);
        xn[row] = nr;
        s_norm  = nr;
    }
    if (row == 0 && tid == 0) aux[0] = 0.0f;
    __syncthreads();
    const float s = 1.0f / (s_norm + 1e-8f);
    ushort4* oh = reinterpret_cast<ushort4*>(Xh + (size_t)row * D_IN);
    ushort4* ol = reinterpret_cast<ushort4*>(Xl + (size_t)row * D_IN);
    ushort4 h, l;
    split2(v0.x*s, h.x, l.x); split2(v0.y*s, h.y, l.y);
    split2(v0.z*s, h.z, l.z); split2(v0.w*s, h.w, l.w);
    oh[tid] = h; ol[tid] = l;
    split2(v1.x*s, h.x, l.x); split2(v1.y*s, h.y, l.y);
    split2(v1.z*s, h.z, l.z); split2(v1.w*s, h.w, l.w);
    oh[tid + 256] = h; ol[tid + 256] = l;
}

// ---------------- Kernel 1-alt (fallback): row norms only ----------------
__global__ __launch_bounds__(256) void norm_kernel(
    const float* __restrict__ x, float* __restrict__ xn, float* __restrict__ aux)
{
    const int row = blockIdx.x, tid = threadIdx.x;
    const float4* xr = reinterpret_cast<const float4*>(x + (size_t)row * D_IN);
    float4 v0 = xr[tid], v1 = xr[tid + 256];
    float ss = v0.x*v0.x + v0.y*v0.y + v0.z*v0.z + v0.w*v0.w
             + v1.x*v1.x + v1.y*v1.y + v1.z*v1.z + v1.w*v1.w;
    #pragma unroll
    for (int off = 32; off > 0; off >>= 1) ss += __shfl_down(ss, off);
    __shared__ float wsum[4];
    if ((tid & 63) == 0) wsum[tid >> 6] = ss;
    __syncthreads();
    if (tid == 0) xn[row] = sqrtf(wsum[0] + wsum[1] + wsum[2] + wsum[3]);
    if (row == 0 && tid == 0) aux[0] = 0.0f;
}

// ---------------- Kernel 1c: split W_enc into bf16 hi/lo ----------------
__global__ __launch_bounds__(256) void split_w_kernel(
    const float* __restrict__ W,
    unsigned short* __restrict__ Wh, unsigned short* __restrict__ Wl)
{
    const int row = blockIdx.x, tid = threadIdx.x;
    const float4* wr = reinterpret_cast<const float4*>(W + (size_t)row * D_IN);
    ushort4* oh = reinterpret_cast<ushort4*>(Wh + (size_t)row * D_IN);
    ushort4* ol = reinterpret_cast<ushort4*>(Wl + (size_t)row * D_IN);
    #pragma unroll
    for (int t = 0; t < 2; ++t) {
        float4 v = wr[tid + t*256];
        ushort4 h, l;
        split2(v.x, h.x, l.x); split2(v.y, h.y, l.y);
        split2(v.z, h.z, l.z); split2(v.w, h.w, l.w);
        oh[tid + t*256] = h; ol[tid + t*256] = l;
    }
}

// ---------------- Kernel 2: encoder GEMM, bf16x2-split MFMA (3 products) ----------------
// C[m,n] = sum_k (Ah+Al)[m,k]*(Bh+Bl)[n,k] + bias[n]   (al*bl dropped)
// 128x128 tile, BK=32, 4 waves (2x2 of 64x64), 16x16x32 MFMA,
// global_load_lds width 16 with BOTH-SIDES XOR swizzle (rule #21):
//   f(r) = (r>>1)&3 on subtile row r (mod 16);
//   stage: lane l fetches global segment (l&3)^f(l>>2) -> LDS stays linear;
//   read:  lane reads LDS segment (l>>4)^f(fr) of row ..+fr.
// => 16-lane read group covers 8 bank-quads x 2 lanes = conflict-free.
#define GLDS16(src, dst) \
    __builtin_amdgcn_global_load_lds( \
        (const __attribute__((address_space(1))) unsigned int*)(src), \
        (__attribute__((address_space(3))) unsigned int*)(dst), 16, 0, 0)

__global__ __launch_bounds__(256) void enc_mfma_kernel(
    const unsigned short* __restrict__ Xh, const unsigned short* __restrict__ Xl,
    const unsigned short* __restrict__ Wh, const unsigned short* __restrict__ Wl,
    const float* __restrict__ bias, float* __restrict__ C)
{
    __shared__ unsigned short sAh[128*32], sAl[128*32], sBh[128*32], sBl[128*32];

    // XCD-aware bijective swizzle (nwg=4096, %8==0): 512-block chunks per XCD.
    const int flat = blockIdx.y * gridDim.x + blockIdx.x;
    const int swz  = (flat & 7) * 512 + (flat >> 3);
    const int bm = swz >> 7;      // 0..31  (4 consecutive bm per XCD chunk)
    const int bn = swz & 127;     // 0..127

    const int tid  = threadIdx.x;
    const int wid  = tid >> 6;    // wave 0..3
    const int lane = tid & 63;
    const int wm = wid >> 1, wn = wid & 1;

    // staging: lane l -> row l>>2 (within 16-row chunk), swizzled 16B segment.
    const int srow = lane >> 2;
    const int sseg = (lane & 3) ^ ((srow >> 1) & 3);   // inverse-swizzled source seg
    const int scol = sseg * 8;                          // elements
    const size_t arow = (size_t)bm*128 + wid*32 + srow;
    const size_t brow = (size_t)bn*128 + wid*32 + srow;
    const unsigned short* gAh = Xh + arow*D_IN + scol;
    const unsigned short* gAl = Xl + arow*D_IN + scol;
    const unsigned short* gBh = Wh + brow*D_IN + scol;
    const unsigned short* gBl = Wl + brow*D_IN + scol;
    const size_t rstep = (size_t)16 * D_IN;   // +16 rows (chunk 1)
    const int ldsA = wid * 1024;              // rows wid*32..wid*32+31

    const int fr  = lane & 15;                                 // fragment row/col
    const int fk2 = (((lane >> 4) ^ ((fr >> 1) & 3))) * 8;     // swizzled k-seg (per-lane const)

    f32x4 acc[4][4] = {};

    for (int k0 = 0; k0 < D_IN; k0 += 32) {
        GLDS16(gAh + k0,         sAh + ldsA);
        GLDS16(gAh + k0 + rstep, sAh + ldsA + 512);
        GLDS16(gAl + k0,         sAl + ldsA);
        GLDS16(gAl + k0 + rstep, sAl + ldsA + 512);
        GLDS16(gBh + k0,         sBh + ldsA);
        GLDS16(gBh + k0 + rstep, sBh + ldsA + 512);
        GLDS16(gBl + k0,         sBl + ldsA);
        GLDS16(gBl + k0 + rstep, sBl + ldsA + 512);
        __syncthreads();   // compiler drains vmcnt(0)+lgkmcnt(0) before s_barrier

        bf16x8 ah[4], al[4], bh[4], bl[4];
        #pragma unroll
        for (int i = 0; i < 4; ++i) {
            const int ar = (wm*64 + i*16 + fr)*32 + fk2;
            ah[i] = *reinterpret_cast<const bf16x8*>(&sAh[ar]);
            al[i] = *reinterpret_cast<const bf16x8*>(&sAl[ar]);
            const int br = (wn*64 + i*16 + fr)*32 + fk2;
            bh[i] = *reinterpret_cast<const bf16x8*>(&sBh[br]);
            bl[i] = *reinterpret_cast<const bf16x8*>(&sBl[br]);
        }
        #pragma unroll
        for (int i = 0; i < 4; ++i)
            #pragma unroll
            for (int j = 0; j < 4; ++j) {
                acc[i][j] = __builtin_amdgcn_mfma_f32_16x16x32_bf16(ah[i], bh[j], acc[i][j], 0, 0, 0);
                acc[i][j] = __builtin_amdgcn_mfma_f32_16x16x32_bf16(ah[i], bl[j], acc[i][j], 0, 0, 0);
                acc[i][j] = __builtin_amdgcn_mfma_f32_16x16x32_bf16(al[i], bh[j], acc[i][j], 0, 0, 0);
            }
        __syncthreads();   // protect LDS before next stage
    }

    // epilogue: C/D layout col=lane&15, row=(lane>>4)*4+reg (m89/m91-verified)
    const int crow = bm*128 + wm*64;
    const int ccol = bn*128 + wn*64;
    #pragma unroll
    for (int j = 0; j < 4; ++j) {
        const int col = ccol + j*16 + fr;
        const float bv = bias[col];
        #pragma unroll
        for (int i = 0; i < 4; ++i) {
            const int r0 = crow + i*16 + (lane >> 4)*4;
            #pragma unroll
            for (int r = 0; r < 4; ++r)
                C[(size_t)(r0 + r)*N_FEAT + col] = acc[i][j][r] + bv;
        }
    }
}

// ---------------- Kernel 2-alt: fp32 SIMT GEMM (fallback when ws small) ----------------
constexpr int BM = 128, BN = 128, BK = 16;
__global__ __launch_bounds__(256) void enc_gemm_kernel(
    const float* __restrict__ X, const float* __restrict__ W,
    const float* __restrict__ bias, const float* __restrict__ xn,
    float* __restrict__ C)
{
    __shared__ float sA[BK][BM + 4];
    __shared__ float sB[BK][BN + 4];
    const int tid = threadIdx.x;
    const int bn = blockIdx.x, bm = blockIdx.y;
    const int tx = tid & 15, ty = tid >> 4;
    const int lrow = tid >> 2;
    const int lq   = (tid & 3) * 4;

    const int arow0 = bm * BM + lrow;
    const float* Ap0 = X + (size_t)arow0 * D_IN + lq;
    const float* Ap1 = Ap0 + (size_t)64 * D_IN;
    const float* Bp0 = W + (size_t)(bn * BN + lrow) * D_IN + lq;
    const float* Bp1 = Bp0 + (size_t)64 * D_IN;

    const float s0 = 1.0f / (xn[arow0] + 1e-8f);
    const float s1 = 1.0f / (xn[arow0 + 64] + 1e-8f);

    float acc[8][8] = {};

    for (int k0 = 0; k0 < D_IN; k0 += BK) {
        float4 a0 = *reinterpret_cast<const float4*>(Ap0 + k0);
        float4 a1 = *reinterpret_cast<const float4*>(Ap1 + k0);
        float4 b0 = *reinterpret_cast<const float4*>(Bp0 + k0);
        float4 b1 = *reinterpret_cast<const float4*>(Bp1 + k0);
        if (k0) __syncthreads();
        sA[lq+0][lrow]    = a0.x * s0; sA[lq+1][lrow]    = a0.y * s0;
        sA[lq+2][lrow]    = a0.z * s0; sA[lq+3][lrow]    = a0.w * s0;
        sA[lq+0][lrow+64] = a1.x * s1; sA[lq+1][lrow+64] = a1.y * s1;
        sA[lq+2][lrow+64] = a1.z * s1; sA[lq+3][lrow+64] = a1.w * s1;
        sB[lq+0][lrow]    = b0.x;      sB[lq+1][lrow]    = b0.y;
        sB[lq+2][lrow]    = b0.z;      sB[lq+3][lrow]    = b0.w;
        sB[lq+0][lrow+64] = b1.x;      sB[lq+1][lrow+64] = b1.y;
        sB[lq+2][lrow+64] = b1.z;      sB[lq+3][lrow+64] = b1.w;
        __syncthreads();
        #pragma unroll
        for (int k = 0; k < BK; ++k) {
            float av[8], bv[8];
            *reinterpret_cast<float4*>(&av[0]) = *reinterpret_cast<const float4*>(&sA[k][ty*8]);
            *reinterpret_cast<float4*>(&av[4]) = *reinterpret_cast<const float4*>(&sA[k][ty*8+4]);
            *reinterpret_cast<float4*>(&bv[0]) = *reinterpret_cast<const float4*>(&sB[k][tx*8]);
            *reinterpret_cast<float4*>(&bv[4]) = *reinterpret_cast<const float4*>(&sB[k][tx*8+4]);
            #pragma unroll
            for (int i = 0; i < 8; ++i)
                #pragma unroll
                for (int j = 0; j < 8; ++j)
                    acc[i][j] += av[i] * bv[j];
        }
    }

    const int crow0 = bm * BM + ty * 8;
    const int ccol0 = bn * BN + tx * 8;
    float bb[8];
    *reinterpret_cast<float4*>(&bb[0]) = *reinterpret_cast<const float4*>(bias + ccol0);
    *reinterpret_cast<float4*>(&bb[4]) = *reinterpret_cast<const float4*>(bias + ccol0 + 4);
    #pragma unroll
    for (int i = 0; i < 8; ++i) {
        float o[8];
        #pragma unroll
        for (int j = 0; j < 8; ++j) o[j] = acc[i][j] + bb[j];
        float* cp = C + (size_t)(crow0 + i) * N_FEAT + ccol0;
        *reinterpret_cast<float4*>(cp)     = *reinterpret_cast<const float4*>(&o[0]);
        *reinterpret_cast<float4*>(cp + 4) = *reinterpret_cast<const float4*>(&o[4]);
    }
}

// ---------------- Kernel 3: exact top-k(32) per row, in-place; optional fused decode ----------------
// Radix-select on 11-bit key prefix, exact tie-break by lowest index (matches lax.top_k).
// DECODE=true: after scatter, compute y[row,:] = (sum relu(v_j)*WT[f_j,:] + bdec) * xn[row].
constexpr int NBINS = 2048;
constexpr int MAXC  = 512;

template <bool DECODE>
__global__ __launch_bounds__(256) void topk_kernel(
    float* __restrict__ hidden, const float* __restrict__ WT,
    const float* __restrict__ bdec, const float* __restrict__ xn,
    float* __restrict__ y)
{
    __shared__ unsigned hist[NBINS];
    __shared__ unsigned tsum[256];
    __shared__ unsigned sufs[256];
    __shared__ unsigned cand_key[MAXC];
    __shared__ float    cand_val[MAXC];
    __shared__ int      cand_idx[MAXC];
    __shared__ float    top_val[TOPK];
    __shared__ int      top_idx[TOPK];
    __shared__ unsigned cnt_top, cnt_cand;
    __shared__ int binB_s;
    __shared__ unsigned above_s;
    __shared__ unsigned long long skey_s[256];
    __shared__ int slot_s[256];

    const int row = blockIdx.x, tid = threadIdx.x;
    float* rowp = hidden + (size_t)row * N_FEAT;
    const float4* row4 = reinterpret_cast<const float4*>(rowp);

    for (int i = tid; i < NBINS; i += 256) hist[i] = 0u;
    if (tid == 0) { cnt_top = 0u; cnt_cand = 0u; }
    __syncthreads();

    // pass 1: histogram of top-11-bit keys
    for (int i = tid; i < N_FEAT/4; i += 256) {
        float4 v = row4[i];
        atomicAdd(&hist[fkey(v.x) >> 21], 1u);
        atomicAdd(&hist[fkey(v.y) >> 21], 1u);
        atomicAdd(&hist[fkey(v.z) >> 21], 1u);
        atomicAdd(&hist[fkey(v.w) >> 21], 1u);
    }
    __syncthreads();

    // suffix sums over 8-bin groups to locate threshold bin
    unsigned s = 0;
    #pragma unroll
    for (int j = 0; j < 8; ++j) s += hist[tid*8 + j];
    tsum[tid] = s;
    __syncthreads();
    unsigned suf = 0;
    for (int u = 0; u < 256; ++u) if (u >= tid) suf += tsum[u];
    sufs[tid] = suf;
    __syncthreads();
    unsigned nxt = (tid == 255) ? 0u : sufs[tid + 1];
    if (suf >= (unsigned)TOPK && nxt < (unsigned)TOPK) {  // exactly one thread
        unsigned cum = nxt;
        for (int j = 7; j >= 0; --j) {
            int b = tid*8 + j;
            unsigned h = hist[b];
            if (cum + h >= (unsigned)TOPK) { binB_s = b; above_s = cum; break; }
            cum += h;
        }
    }
    __syncthreads();
    const int binB = binB_s;
    const unsigned above = above_s;

    // pass 2 (re-read): definite top-k (bin > binB) + boundary candidates
    for (int i = tid; i < N_FEAT/4; i += 256) {
        float4 v = row4[i];
        float vals[4] = {v.x, v.y, v.z, v.w};
        #pragma unroll
        for (int c = 0; c < 4; ++c) {
            unsigned key = fkey(vals[c]);
            int bin = (int)(key >> 21);
            if (bin > binB) {
                unsigned p = atomicAdd(&cnt_top, 1u);
                top_val[p] = vals[c]; top_idx[p] = i*4 + c;
            } else if (bin == binB) {
                unsigned p = atomicAdd(&cnt_cand, 1u);
                if (p < (unsigned)MAXC) {
                    cand_key[p] = key; cand_val[p] = vals[c]; cand_idx[p] = i*4 + c;
                }
            }
        }
    }
    __syncthreads();
    int ncand = (int)cnt_cand; if (ncand > MAXC) ncand = MAXC;
    const int r = TOPK - (int)above;

    // select r largest boundary candidates (key desc, idx asc on ties)
    for (int sel = 0; sel < r; ++sel) {
        unsigned long long best = 0ull; int bslot = -1;
        for (int c = tid; c < ncand; c += 256) {
            unsigned k2 = cand_key[c];
            if (k2 == 0u) continue;  // taken
            unsigned long long sk =
                ((unsigned long long)k2 << 32) | (unsigned)(~(unsigned)cand_idx[c]);
            if (sk > best) { best = sk; bslot = c; }
        }
        skey_s[tid] = best; slot_s[tid] = bslot;
        __syncthreads();
        for (int st = 128; st > 0; st >>= 1) {
            if (tid < st && skey_s[tid + st] > skey_s[tid]) {
                skey_s[tid] = skey_s[tid + st]; slot_s[tid] = slot_s[tid + st];
            }
            __syncthreads();
        }
        if (tid == 0) {
            int sl = slot_s[0];
            cand_key[sl] = 0u;
            top_val[(int)above + sel] = cand_val[sl];
            top_idx[(int)above + sel] = cand_idx[sl];
        }
        __syncthreads();
    }

    // zero the row, scatter relu(topk)
    float4 z = make_float4(0.f, 0.f, 0.f, 0.f);
    float4* w4 = reinterpret_cast<float4*>(rowp);
    for (int i = tid; i < N_FEAT/4; i += 256) w4[i] = z;
    __syncthreads();
    if (tid < TOPK) rowp[top_idx[tid]] = fmaxf(top_val[tid], 0.0f);

    if (DECODE) {
        // fused decode: nz list already in LDS — saves the 256MB hidden re-scan
        // and one launch vs a separate decode kernel.
        const float4* b4 = reinterpret_cast<const float4*>(bdec);
        float4 acc0 = b4[tid], acc1 = b4[tid + 256];
        #pragma unroll 1
        for (int j = 0; j < TOPK; ++j) {
            const float v = fmaxf(top_val[j], 0.0f);   // uniform across block
            if (v == 0.0f) continue;
            const float4* wr = reinterpret_cast<const float4*>(
                WT + (size_t)top_idx[j] * D_OUT);
            float4 w0 = wr[tid], w1 = wr[tid + 256];
            acc0.x += v*w0.x; acc0.y += v*w0.y; acc0.z += v*w0.z; acc0.w += v*w0.w;
            acc1.x += v*w1.x; acc1.y += v*w1.y; acc1.z += v*w1.z; acc1.w += v*w1.w;
        }
        const float xs = xn[row];
        acc0.x *= xs; acc0.y *= xs; acc0.z *= xs; acc0.w *= xs;
        acc1.x *= xs; acc1.y *= xs; acc1.z *= xs; acc1.w *= xs;
        float4* y4 = reinterpret_cast<float4*>(y + (size_t)row * D_OUT);
        y4[tid] = acc0; y4[tid + 256] = acc1;
    }
}

// ---------------- Kernel 4: transpose W_dec (D_OUT,N_FEAT)->(N_FEAT,D_OUT) ----------------
__global__ __launch_bounds__(256) void transpose_kernel(
    const float* __restrict__ W, float* __restrict__ WT)
{
    __shared__ float tile[32][33];
    const int f0 = blockIdx.x * 32, d0 = blockIdx.y * 32;
    const int tx = threadIdx.x & 31, ty = threadIdx.x >> 5;  // ty 0..7
    #pragma unroll
    for (int s2 = 0; s2 < 32; s2 += 8)
        tile[ty + s2][tx] = W[(size_t)(d0 + ty + s2) * N_FEAT + f0 + tx];
    __syncthreads();
    #pragma unroll
    for (int s2 = 0; s2 < 32; s2 += 8)
        WT[(size_t)(f0 + ty + s2) * D_OUT + d0 + tx] = tile[tx][ty + s2];
}

// ---------------- Kernel 5 (tiny-ws fallback): strided column-gather decode ----------------
__global__ __launch_bounds__(256) void decode_g_kernel(
    const float* __restrict__ Wd, const float* __restrict__ hidden,
    const float* __restrict__ bdec, const float* __restrict__ xn,
    float* __restrict__ y)
{
    __shared__ float nzv[64]; __shared__ int nzi[64]; __shared__ int nzc;
    const int row = blockIdx.x, tid = threadIdx.x;
    if (tid == 0) nzc = 0;
    __syncthreads();
    const float4* h4 = reinterpret_cast<const float4*>(hidden + (size_t)row * N_FEAT);
    for (int i = tid; i < N_FEAT/4; i += 256) {
        float4 v = h4[i];
        if (v.x != 0.f) { int p = atomicAdd(&nzc, 1); if (p < 64) { nzv[p] = v.x; nzi[p] = i*4;   } }
        if (v.y != 0.f) { int p = atomicAdd(&nzc, 1); if (p < 64) { nzv[p] = v.y; nzi[p] = i*4+1; } }
        if (v.z != 0.f) { int p = atomicAdd(&nzc, 1); if (p < 64) { nzv[p] = v.z; nzi[p] = i*4+2; } }
        if (v.w != 0.f) { int p = atomicAdd(&nzc, 1); if (p < 64) { nzv[p] = v.w; nzi[p] = i*4+3; } }
    }
    __syncthreads();
    int cnt = nzc; if (cnt > 64) cnt = 64;
    const int d0 = tid * 4, d1 = d0 + 1024;
    float a[8];
    a[0]=bdec[d0]; a[1]=bdec[d0+1]; a[2]=bdec[d0+2]; a[3]=bdec[d0+3];
    a[4]=bdec[d1]; a[5]=bdec[d1+1]; a[6]=bdec[d1+2]; a[7]=bdec[d1+3];
    for (int j = 0; j < cnt; ++j) {
        float v = nzv[j]; int f = nzi[j];
        a[0] += v * Wd[(size_t)(d0+0)*N_FEAT + f];
        a[1] += v * Wd[(size_t)(d0+1)*N_FEAT + f];
        a[2] += v * Wd[(size_t)(d0+2)*N_FEAT + f];
        a[3] += v * Wd[(size_t)(d0+3)*N_FEAT + f];
        a[4] += v * Wd[(size_t)(d1+0)*N_FEAT + f];
        a[5] += v * Wd[(size_t)(d1+1)*N_FEAT + f];
        a[6] += v * Wd[(size_t)(d1+2)*N_FEAT + f];
        a[7] += v * Wd[(size_t)(d1+3)*N_FEAT + f];
    }
    const float xs = xn[row];
    float* yr = y + (size_t)row * D_OUT;
    yr[d0]=a[0]*xs; yr[d0+1]=a[1]*xs; yr[d0+2]=a[2]*xs; yr[d0+3]=a[3]*xs;
    yr[d1]=a[4]*xs; yr[d1+1]=a[5]*xs; yr[d1+2]=a[6]*xs; yr[d1+3]=a[7]*xs;
}

extern "C" void kernel_launch(void* const* d_in, const int* in_sizes, int n_in,
                              void* d_out, int out_size, void* d_ws, size_t ws_size,
                              hipStream_t stream)
{
    const float* x     = (const float*)d_in[0];
    const float* W_enc = (const float*)d_in[1];
    const float* b_enc = (const float*)d_in[2];
    const float* W_dec = (const float*)d_in[3];
    const float* b_dec = (const float*)d_in[4];

    float* out    = (float*)d_out;
    float* y      = out;                                   // (B, D_OUT)
    float* hidden = out + (size_t)BROWS * D_OUT;           // (B, N_FEAT)
    float* aux    = hidden + (size_t)BROWS * N_FEAT;       // scalar
    float* xn     = aux + 1;                               // (B,)

    // ws layout: region1 (128MB) = Wh,Wl (bf16) during GEMM, WT (f32) after
    //            region2 (32MB)  = Xh,Xl (bf16)
    const size_t nW = (size_t)N_FEAT * D_IN;               // 33,554,432 elems
    const size_t nX = (size_t)BROWS * D_IN;                // 8,388,608 elems
    unsigned short* Wh = (unsigned short*)d_ws;
    unsigned short* Wl = Wh + nW;
    float*          WT = (float*)d_ws;                     // aliases Wh/Wl (temporally disjoint)
    unsigned short* Xh = (unsigned short*)(Wl + nW);
    unsigned short* Xl = Xh + nX;
    const size_t need_full = 2*nW*sizeof(unsigned short)   // region1: 128MB (== N_FEAT*D_OUT*4)
                           + 2*nX*sizeof(unsigned short);  // region2: 32MB  -> 160MB total
    const size_t need_wt   = (size_t)N_FEAT*D_OUT*sizeof(float);     // 128MB

    if (ws_size >= need_full) {
        norm_split_x_kernel<<<BROWS, 256, 0, stream>>>(x, xn, aux, Xh, Xl);
        split_w_kernel<<<N_FEAT, 256, 0, stream>>>(W_enc, Wh, Wl);
        enc_mfma_kernel<<<dim3(N_FEAT/128, BROWS/128), 256, 0, stream>>>(
            Xh, Xl, Wh, Wl, b_enc, hidden);
        // transpose AFTER the GEMM: WT overwrites the Wh/Wl region
        transpose_kernel<<<dim3(N_FEAT/32, D_OUT/32), 256, 0, stream>>>(W_dec, WT);
        topk_kernel<true><<<BROWS, 256, 0, stream>>>(hidden, WT, b_dec, xn, y);
    } else if (ws_size >= need_wt) {
        float* WT0 = (float*)d_ws;
        norm_kernel<<<BROWS, 256, 0, stream>>>(x, xn, aux);
        enc_gemm_kernel<<<dim3(N_FEAT/BN, BROWS/BM), 256, 0, stream>>>(
            x, W_enc, b_enc, xn, hidden);
        transpose_kernel<<<dim3(N_FEAT/32, D_OUT/32), 256, 0, stream>>>(W_dec, WT0);
        topk_kernel<true><<<BROWS, 256, 0, stream>>>(hidden, WT0, b_dec, xn, y);
    } else {
        norm_kernel<<<BROWS, 256, 0, stream>>>(x, xn, aux);
        enc_gemm_kernel<<<dim3(N_FEAT/BN, BROWS/BM), 256, 0, stream>>>(
            x, W_enc, b_enc, xn, hidden);
        topk_kernel<false><<<BROWS, 256, 0, stream>>>(hidden, nullptr, nullptr, nullptr, nullptr);
        decode_g_kernel<<<BROWS, 256, 0, stream>>>(W_dec, hidden, b_dec, xn, y);
    }
}